// Round 6
// baseline (198.679 us; speedup 1.0000x reference)
//
#include <hip/hip_runtime.h>
#include <stdint.h>

#define DIM 128

typedef __attribute__((ext_vector_type(8))) short short8;
typedef __attribute__((ext_vector_type(4))) float f32x4;

static __device__ __forceinline__ uint16_t f2bf(float f) {
  uint32_t u = __builtin_bit_cast(uint32_t, f);
  uint32_t r = (u + 0x7fffu + ((u >> 16) & 1u)) >> 16;  // RNE
  return (uint16_t)r;
}
static __device__ __forceinline__ uint32_t pack2(float a, float b) {
  return (uint32_t)f2bf(a) | ((uint32_t)f2bf(b) << 16);
}
static __device__ __forceinline__ void add4(float4& a, const float4 b) {
  a.x += b.x; a.y += b.y; a.z += b.z; a.w += b.w;
}
static __device__ __forceinline__ float bflo(uint32_t u) {
  return __builtin_bit_cast(float, (uint32_t)(u << 16));
}
static __device__ __forceinline__ float bfhi(uint32_t u) {
  return __builtin_bit_cast(float, (uint32_t)(u & 0xffff0000u));
}

// ---------------- prep: x->bf16 convert + edge histogram + B table ----------------
// gid < n_conv : convert 8 f32 of x -> 8 bf16 (uint4 write) into x16
// gid < 16384  : build frag-order bf16 B table (64KB, L2-hot for the GEMM)
// gid < n_edge : histogram of dst
__global__ __launch_bounds__(256) void prep_kernel(
    const float* __restrict__ x, const int* __restrict__ dst,
    int* __restrict__ counts, int n_edge,
    const float* __restrict__ W1, const float* __restrict__ W2,
    uint32_t* __restrict__ b_tab, uint32_t* __restrict__ x16, int n_conv) {
  const int gid = blockIdx.x * 256 + threadIdx.x;
  if (gid < n_conv) {
    const float4* p = reinterpret_cast<const float4*>(x) + (size_t)gid * 2;
    const float4 u = p[0], v = p[1];
    uint4 o;
    o.x = pack2(u.x, u.y); o.y = pack2(u.z, u.w);
    o.z = pack2(v.x, v.y); o.w = pack2(v.z, v.w);
    reinterpret_cast<uint4*>(x16)[gid] = o;
  }
  if (gid < 16384) {
    // frag(kst,ct): lane ln, elems j,j+1 -> B[k=kst*32+(ln>>4)*8+j][c=ct*16+(ln&15)]
    const int e = gid << 1;
    const int kst = e >> 12;
    const int ct  = (e >> 9) & 7;
    const int ln  = (e >> 3) & 63;
    const int j   = e & 7;
    const int k   = kst * 32 + ((ln >> 4) << 3) + j;
    const int c   = ct * 16 + (ln & 15);
    const float* wp = (k < 128) ? (W1 + c * 128 + k) : (W2 + c * 128 + (k - 128));
    b_tab[gid] = pack2(wp[0], wp[1]);
  }
  if (gid < n_edge) atomicAdd(&counts[dst[gid]], 1);
}

// Block-level inclusive scan (1024/block); row_ptr[i+1] = partial, bsum[b] = total.
__global__ __launch_bounds__(1024) void scan1_kernel(
    const int* __restrict__ counts, int* __restrict__ row_ptr,
    int* __restrict__ bsum, int n) {
  __shared__ int sm[1024];
  const int t = threadIdx.x, i = blockIdx.x * 1024 + t;
  int v = (i < n) ? counts[i] : 0;
  sm[t] = v;
  __syncthreads();
  for (int off = 1; off < 1024; off <<= 1) {
    int a = (t >= off) ? sm[t - off] : 0;
    __syncthreads();
    sm[t] += a;
    __syncthreads();
  }
  if (i < n) row_ptr[i + 1] = sm[t];
  if (t == 1023) bsum[blockIdx.x] = sm[t];
}

// Apply block offsets; wave 0 computes this block's single bsum prefix inline.
__global__ __launch_bounds__(256) void scan3_kernel(
    int* __restrict__ row_ptr, int* __restrict__ cursor,
    const int* __restrict__ bsum, int n) {
  __shared__ int soff;
  const int t = threadIdx.x;
  const int nbp = (int)(blockIdx.x >> 2);  // # scan1 blocks before mine
  if (t < 64) {
    int acc = 0;
    for (int b = t; b < nbp; b += 64) acc += bsum[b];
    for (int off = 32; off; off >>= 1) acc += __shfl_down(acc, off);
    if (t == 0) soff = acc;
  }
  __syncthreads();
  const int off = soff;
  const int i = blockIdx.x * 256 + t;
  if (i < n) {
    const int v = row_ptr[i + 1] + off;
    row_ptr[i + 1] = v;
    if (i + 1 < n) cursor[i + 1] = v;
    if (i == 0) { row_ptr[0] = 0; cursor[0] = 0; }
  }
}

__global__ __launch_bounds__(256) void fill_kernel(
    const int* __restrict__ src, const int* __restrict__ dst,
    int* __restrict__ cursor, int* __restrict__ sorted, int n_edge) {
  const int e = blockIdx.x * 256 + threadIdx.x;
  if (e < n_edge) {
    const int pos = atomicAdd(&cursor[dst[e]], 1);
    sorted[pos] = src[e];
  }
}

// ---------------- Fused aggregate + GEMM, bf16 gather ----------------
// Block = 4 independent waves, each owns 16 dst rows; wave = 4 groups of 16
// lanes; group g owns rows g*4..g*4+3 which are CONTIGUOUS in CSR -> walk one
// flat edge stream [beg0,end3) in 8-edge halves, double-buffered (A/B uint4[8]
// = 64 VGPRs genuinely in flight), flushing acc->LDS at row boundaries.
// Phase B: 8x8 MFMA 16x16x32 from own LDS tile x global b_tab. No barriers.
__global__ __launch_bounds__(256, 4) void fused_bf16_kernel(
    const uint16_t* __restrict__ x16, const int* __restrict__ row_ptr,
    const int* __restrict__ sorted, const float* __restrict__ degree,
    const int* __restrict__ self_ids, const uint32_t* __restrict__ b_tab,
    float* __restrict__ out, int n_dst)
{
  __shared__ uint32_t As[4][16][132];   // per-wave tiles, stride 528B
  const int tid = threadIdx.x;
  const int w = tid >> 6, lane = tid & 63;
  const int g = lane >> 4, li = lane & 15;
  const int rbase = blockIdx.x * 64 + w * 16;

  // Wave-wide metadata prefetch.
  int rp = 0, sid_all = 0;
  float deg_all = 1.f;
  if (lane < 17) {
    const int idx = rbase + lane;
    rp = row_ptr[idx > n_dst ? n_dst : idx];
  }
  if (lane < 16) {
    const int r = rbase + lane;
    const int rc = (r < n_dst) ? r : 0;
    sid_all = self_ids[rc];
    deg_all = degree[rc];
  }

  const int b0 = __shfl(rp, g * 4 + 0);
  const int e1 = __shfl(rp, g * 4 + 1) - b0;   // relative row boundaries
  const int e2 = __shfl(rp, g * 4 + 2) - b0;
  const int e3 = __shfl(rp, g * 4 + 3) - b0;
  const int P  = __shfl(rp, g * 4 + 4) - b0;
  const float inv0 = 1.0f / __shfl(deg_all, g * 4 + 0);
  const float inv1 = 1.0f / __shfl(deg_all, g * 4 + 1);
  const float inv2 = 1.0f / __shfl(deg_all, g * 4 + 2);
  const float inv3 = 1.0f / __shfl(deg_all, g * 4 + 3);
  const int sid0 = __shfl(sid_all, g * 4 + 0);
  const int sid1 = __shfl(sid_all, g * 4 + 1);
  const int sid2 = __shfl(sid_all, g * 4 + 2);
  const int sid3 = __shfl(sid_all, g * 4 + 3);

  // Self rows: 4 independent 16B loads, consumed after the edge loop.
  const uint4 sv0 = *reinterpret_cast<const uint4*>(x16 + (size_t)sid0 * DIM + li * 8);
  const uint4 sv1 = *reinterpret_cast<const uint4*>(x16 + (size_t)sid1 * DIM + li * 8);
  const uint4 sv2 = *reinterpret_cast<const uint4*>(x16 + (size_t)sid2 * DIM + li * 8);
  const uint4 sv3 = *reinterpret_cast<const uint4*>(x16 + (size_t)sid3 * DIM + li * 8);

  // Edge-id chunks of 16 (lane li holds position chunkbase+li), prefetched
  // one chunk ahead.
  int ids = (li < P) ? sorted[b0 + li] : 0;
  int idsN = 0;

  float a[8] = {0.f, 0.f, 0.f, 0.f, 0.f, 0.f, 0.f, 0.f};
  int rcur = 0;

  auto FLUSH = [&]() {
    const float iv = (rcur == 0) ? inv0 : (rcur == 1) ? inv1 : (rcur == 2) ? inv2 : inv3;
    uint4 pa;
    pa.x = pack2(a[0] * iv, a[1] * iv);
    pa.y = pack2(a[2] * iv, a[3] * iv);
    pa.z = pack2(a[4] * iv, a[5] * iv);
    pa.w = pack2(a[6] * iv, a[7] * iv);
    *reinterpret_cast<uint4*>(&As[w][g * 4 + rcur][li * 4]) = pa;
#pragma unroll
    for (int q = 0; q < 8; ++q) a[q] = 0.f;
  };

  uint4 A[8], B[8];

  auto ISSUE = [&](uint4 (&buf)[8], int e0) {
    if ((e0 & 15) == 0 && e0 > 0) ids = idsN;        // enter new chunk
    if ((e0 & 15) == 8 && e0 + 8 < P)                // prefetch next chunk
      idsN = (li < P - (e0 + 8)) ? sorted[b0 + e0 + 8 + li] : 0;
#pragma unroll
    for (int u = 0; u < 8; ++u) {
      const int ee = e0 + u;
      int s = __shfl(ids, g * 16 + (ee & 15));
      s = (ee < P) ? s : 0;                          // tail: harmless row-0 load
      buf[u] = *reinterpret_cast<const uint4*>(x16 + (size_t)s * DIM + li * 8);
    }
  };

  auto CONSUME = [&](const uint4 (&buf)[8], int jb) {
#pragma unroll
    for (int u = 0; u < 8; ++u) {
      const int j = jb + u;
      if (j < P) {
        while (rcur < 3) {
          const int bnext = (rcur == 0) ? e1 : (rcur == 1) ? e2 : e3;
          if (j < bnext) break;
          FLUSH();
          ++rcur;
        }
        const uint4 q = buf[u];
        a[0] += bflo(q.x); a[1] += bfhi(q.x);
        a[2] += bflo(q.y); a[3] += bfhi(q.y);
        a[4] += bflo(q.z); a[5] += bfhi(q.z);
        a[6] += bflo(q.w); a[7] += bfhi(q.w);
      }
    }
  };

  if (P > 0) {
    ISSUE(A, 0);
    int jb = 0;
    for (;;) {
      if (jb + 8 < P) ISSUE(B, jb + 8);
      CONSUME(A, jb);
      jb += 8;
      if (jb >= P) break;
      if (jb + 8 < P) ISSUE(A, jb + 8);
      CONSUME(B, jb);
      jb += 8;
      if (jb >= P) break;
    }
  }
  while (rcur < 4) { FLUSH(); ++rcur; }

  // Self rows -> LDS (already bf16, direct copy).
  *reinterpret_cast<uint4*>(&As[w][g * 4 + 0][64 + li * 4]) = sv0;
  *reinterpret_cast<uint4*>(&As[w][g * 4 + 1][64 + li * 4]) = sv1;
  *reinterpret_cast<uint4*>(&As[w][g * 4 + 2][64 + li * 4]) = sv2;
  *reinterpret_cast<uint4*>(&As[w][g * 4 + 3][64 + li * 4]) = sv3;

  // Phase B: A-frag lane ln holds A[row=ln&15][k=kst*32+(ln>>4)*8+j], j=0..7.
  // Wave-synchronous: this wave wrote its whole tile; no barrier needed.
  const uint32_t* Arow = &As[w][lane & 15][(lane >> 4) << 2];
  const uint16_t* Bt = (const uint16_t*)b_tab;
  f32x4 acc[8] = {};
#pragma unroll
  for (int kst = 0; kst < 8; ++kst) {
    const short8 av = *reinterpret_cast<const short8*>(Arow + kst * 16);
#pragma unroll
    for (int ct = 0; ct < 8; ++ct) {
      const short8 bv = *reinterpret_cast<const short8*>(Bt + (kst * 8 + ct) * 512 + lane * 8);
      acc[ct] = __builtin_amdgcn_mfma_f32_16x16x32_bf16(av, bv, acc[ct], 0, 0, 0);
    }
  }

  // C/D (m89): col = lane&15, row = (lane>>4)*4 + reg.
  const int rout = rbase + ((lane >> 4) << 2);
  const int ccol = lane & 15;
#pragma unroll
  for (int ct = 0; ct < 8; ++ct) {
#pragma unroll
    for (int j = 0; j < 4; ++j) {
      const int row = rout + j;
      if (row < n_dst) out[(size_t)row * DIM + ct * 16 + ccol] = acc[ct][j];
    }
  }
}

// ---------------- Fallback: round-5 f32 fused kernel (used if ws too small) --
__global__ __launch_bounds__(256, 4) void fused_f32_kernel(
    const float* __restrict__ x, const int* __restrict__ row_ptr,
    const int* __restrict__ sorted, const float* __restrict__ degree,
    const int* __restrict__ self_ids, const uint32_t* __restrict__ b_tab,
    float* __restrict__ out, int n_dst)
{
  __shared__ uint32_t As[4][16][132];
  const int tid = threadIdx.x;
  const int w = tid >> 6, lane = tid & 63;
  const int g = lane >> 4, li = lane & 15;
  const int rbase = blockIdx.x * 64 + w * 16;

  int rp = 0, sid_all = 0;
  float deg_all = 1.f;
  if (lane < 17) {
    const int idx = rbase + lane;
    rp = row_ptr[idx > n_dst ? n_dst : idx];
  }
  if (lane < 16) {
    const int r = rbase + lane;
    const int rc = (r < n_dst) ? r : 0;
    sid_all = self_ids[rc];
    deg_all = degree[rc];
  }

  int beg[4], end[4], sid[4];
  float inv[4];
#pragma unroll
  for (int r = 0; r < 4; ++r) {
    const int rr = g * 4 + r;
    beg[r] = __shfl(rp, rr);
    end[r] = __shfl(rp, rr + 1);
    sid[r] = __shfl(sid_all, rr);
    inv[r] = 1.0f / __shfl(deg_all, rr);
  }
  int ids[4];
#pragma unroll
  for (int r = 0; r < 4; ++r)
    ids[r] = (li < end[r] - beg[r]) ? sorted[beg[r] + li] : 0;
  float4 s0[4], s1[4];
#pragma unroll
  for (int r = 0; r < 4; ++r) {
    const float4* xs = reinterpret_cast<const float4*>(x + (size_t)sid[r] * DIM + li * 8);
    s0[r] = xs[0];
    s1[r] = xs[1];
  }

#pragma unroll
  for (int r = 0; r < 4; ++r) {
    const int rr = g * 4 + r;
    float4 a0 = {0.f, 0.f, 0.f, 0.f}, a1 = {0.f, 0.f, 0.f, 0.f};
    int base = beg[r];
    int chunk = ids[r];
    for (;;) {
      const int m = end[r] - base;
      const int cnt = m < 16 ? m : 16;
      for (int jb = 0; jb < cnt; jb += 4) {
        float4 v0[4], v1[4];
#pragma unroll
        for (int u = 0; u < 4; ++u) {
          const int s = __shfl(chunk, g * 16 + ((jb + u) & 15));
          const float4* p = reinterpret_cast<const float4*>(x + (size_t)s * DIM + li * 8);
          v0[u] = p[0];
          v1[u] = p[1];
        }
#pragma unroll
        for (int u = 0; u < 4; ++u) {
          if (jb + u < cnt) { add4(a0, v0[u]); add4(a1, v1[u]); }
        }
      }
      base += 16;
      if (base >= end[r]) break;
      chunk = (li < end[r] - base) ? sorted[base + li] : 0;
    }

    uint4 pa;
    pa.x = pack2(a0.x * inv[r], a0.y * inv[r]);
    pa.y = pack2(a0.z * inv[r], a0.w * inv[r]);
    pa.z = pack2(a1.x * inv[r], a1.y * inv[r]);
    pa.w = pack2(a1.z * inv[r], a1.w * inv[r]);
    *reinterpret_cast<uint4*>(&As[w][rr][li * 4]) = pa;
    uint4 ps;
    ps.x = pack2(s0[r].x, s0[r].y);
    ps.y = pack2(s0[r].z, s0[r].w);
    ps.z = pack2(s1[r].x, s1[r].y);
    ps.w = pack2(s1[r].z, s1[r].w);
    *reinterpret_cast<uint4*>(&As[w][rr][64 + li * 4]) = ps;
  }

  const uint32_t* Arow = &As[w][lane & 15][(lane >> 4) << 2];
  const uint16_t* Bt = (const uint16_t*)b_tab;
  f32x4 acc[8] = {};
#pragma unroll
  for (int kst = 0; kst < 8; ++kst) {
    const short8 av = *reinterpret_cast<const short8*>(Arow + kst * 16);
#pragma unroll
    for (int ct = 0; ct < 8; ++ct) {
      const short8 bv = *reinterpret_cast<const short8*>(Bt + (kst * 8 + ct) * 512 + lane * 8);
      acc[ct] = __builtin_amdgcn_mfma_f32_16x16x32_bf16(av, bv, acc[ct], 0, 0, 0);
    }
  }

  const int rout = rbase + ((lane >> 4) << 2);
  const int ccol = lane & 15;
#pragma unroll
  for (int ct = 0; ct < 8; ++ct) {
#pragma unroll
    for (int j = 0; j < 4; ++j) {
      const int row = rout + j;
      if (row < n_dst) out[(size_t)row * DIM + ct * 16 + ccol] = acc[ct][j];
    }
  }
}

extern "C" void kernel_launch(void* const* d_in, const int* in_sizes, int n_in,
                              void* d_out, int out_size, void* d_ws, size_t ws_size,
                              hipStream_t stream) {
  const float* x        = (const float*)d_in[0];
  const float* W1       = (const float*)d_in[1];
  const float* W2       = (const float*)d_in[2];
  const float* degree   = (const float*)d_in[3];
  const int*   src_idx  = (const int*)d_in[4];
  const int*   dst_idx  = (const int*)d_in[5];
  const int*   self_ids = (const int*)d_in[6];
  float* out = (float*)d_out;
  const int n_dst  = in_sizes[3];
  const int n_edge = in_sizes[4];
  const int n_src  = in_sizes[0] / DIM;

  // ws: counts | row_ptr | cursor | bsum | sorted | b_tab | x16(51MB, optional)
  auto align256 = [](size_t v) { return (v + 255) & ~(size_t)255; };
  char* ws = (char*)d_ws;
  size_t o_counts = 0;
  size_t o_rowptr = align256(o_counts + (size_t)n_dst * 4);
  size_t o_cursor = align256(o_rowptr + (size_t)(n_dst + 1) * 4);
  size_t o_bsum   = align256(o_cursor + (size_t)n_dst * 4);
  size_t o_sorted = align256(o_bsum + 1024 * 4);
  size_t o_btab   = align256(o_sorted + (size_t)n_edge * 4);
  size_t o_x16    = align256(o_btab + 16384 * 4);
  const size_t x16_bytes = (size_t)n_src * DIM * 2;
  int* counts  = (int*)(ws + o_counts);
  int* row_ptr = (int*)(ws + o_rowptr);
  int* cursor  = (int*)(ws + o_cursor);
  int* bsum    = (int*)(ws + o_bsum);
  int* sorted  = (int*)(ws + o_sorted);
  uint32_t* b_tab = (uint32_t*)(ws + o_btab);
  uint32_t* x16   = (uint32_t*)(ws + o_x16);

  const bool use_bf16 = (ws_size >= o_x16 + x16_bytes);
  const int n_conv = use_bf16 ? n_src * (DIM / 8) : 0;  // threads converting 8 elems

  const int nb = (n_dst + 1023) >> 10;
  int prep_work = n_edge > 16384 ? n_edge : 16384;
  if (n_conv > prep_work) prep_work = n_conv;

  hipMemsetAsync(counts, 0, (size_t)n_dst * 4, stream);
  prep_kernel<<<(prep_work + 255) / 256, 256, 0, stream>>>(
      x, dst_idx, counts, n_edge, W1, W2, b_tab, x16, n_conv);
  scan1_kernel<<<nb, 1024, 0, stream>>>(counts, row_ptr, bsum, n_dst);
  scan3_kernel<<<(n_dst + 255) / 256, 256, 0, stream>>>(row_ptr, cursor, bsum, n_dst);
  fill_kernel<<<(n_edge + 255) / 256, 256, 0, stream>>>(src_idx, dst_idx, cursor,
                                                        sorted, n_edge);
  if (use_bf16) {
    fused_bf16_kernel<<<(n_dst + 63) / 64, 256, 0, stream>>>(
        (const uint16_t*)x16, row_ptr, sorted, degree, self_ids, b_tab, out, n_dst);
  } else {
    fused_f32_kernel<<<(n_dst + 63) / 64, 256, 0, stream>>>(
        x, row_ptr, sorted, degree, self_ids, b_tab, out, n_dst);
  }
}

// Round 7
// 127.168 us; speedup vs baseline: 1.5623x; 1.5623x over previous
//
#include <hip/hip_runtime.h>
#include <stdint.h>

#define DIM 128

typedef __attribute__((ext_vector_type(8))) short short8;
typedef __attribute__((ext_vector_type(4))) float f32x4;

static __device__ __forceinline__ uint16_t f2bf(float f) {
  uint32_t u = __builtin_bit_cast(uint32_t, f);
  uint32_t r = (u + 0x7fffu + ((u >> 16) & 1u)) >> 16;  // RNE
  return (uint16_t)r;
}
static __device__ __forceinline__ uint32_t pack2(float a, float b) {
  return (uint32_t)f2bf(a) | ((uint32_t)f2bf(b) << 16);
}

// ---------------- CSR build ----------------
// hist: edge histogram; first 64 blocks also build the frag-order bf16 B table.
__global__ __launch_bounds__(256) void hist_kernel(
    const int* __restrict__ dst, int* __restrict__ counts, int n_edge,
    const float* __restrict__ W1, const float* __restrict__ W2,
    uint32_t* __restrict__ b_tab) {
  const int gid = blockIdx.x * 256 + threadIdx.x;
  if (gid < 16384) {
    // frag(kst,ct): lane ln, elems j,j+1 -> B[k=kst*32+(ln>>4)*8+j][c=ct*16+(ln&15)]
    const int e = gid << 1;
    const int kst = e >> 12;
    const int ct  = (e >> 9) & 7;
    const int ln  = (e >> 3) & 63;
    const int j   = e & 7;
    const int k   = kst * 32 + ((ln >> 4) << 3) + j;
    const int c   = ct * 16 + (ln & 15);
    const float* wp = (k < 128) ? (W1 + c * 128 + k) : (W2 + c * 128 + (k - 128));
    b_tab[gid] = pack2(wp[0], wp[1]);
  }
  if (gid < n_edge) atomicAdd(&counts[dst[gid]], 1);
}

__global__ __launch_bounds__(1024) void scan1_kernel(
    const int* __restrict__ counts, int* __restrict__ row_ptr,
    int* __restrict__ bsum, int n) {
  __shared__ int sm[1024];
  const int t = threadIdx.x, i = blockIdx.x * 1024 + t;
  int v = (i < n) ? counts[i] : 0;
  sm[t] = v;
  __syncthreads();
  for (int off = 1; off < 1024; off <<= 1) {
    int a = (t >= off) ? sm[t - off] : 0;
    __syncthreads();
    sm[t] += a;
    __syncthreads();
  }
  if (i < n) row_ptr[i + 1] = sm[t];
  if (t == 1023) bsum[blockIdx.x] = sm[t];
}

// Apply block offsets; wave 0 computes this block's single bsum prefix inline.
__global__ __launch_bounds__(256) void scan3_kernel(
    int* __restrict__ row_ptr, int* __restrict__ cursor,
    const int* __restrict__ bsum, int n) {
  __shared__ int soff;
  const int t = threadIdx.x;
  const int nbp = (int)(blockIdx.x >> 2);
  if (t < 64) {
    int acc = 0;
    for (int b = t; b < nbp; b += 64) acc += bsum[b];
    for (int off = 32; off; off >>= 1) acc += __shfl_down(acc, off);
    if (t == 0) soff = acc;
  }
  __syncthreads();
  const int off = soff;
  const int i = blockIdx.x * 256 + t;
  if (i < n) {
    const int v = row_ptr[i + 1] + off;
    row_ptr[i + 1] = v;
    if (i + 1 < n) cursor[i + 1] = v;
    if (i == 0) { row_ptr[0] = 0; cursor[0] = 0; }
  }
}

__global__ __launch_bounds__(256) void fill_kernel(
    const int* __restrict__ src, const int* __restrict__ dst,
    int* __restrict__ cursor, int* __restrict__ sorted, int n_edge) {
  const int e = blockIdx.x * 256 + threadIdx.x;
  if (e < n_edge) {
    const int pos = atomicAdd(&cursor[dst[e]], 1);
    sorted[pos] = src[e];
  }
}

// ---- inline-asm gather primitives (forced MLP; rule #18 sched_barrier) ----
#define GLD(dstv, ptr) \
  asm volatile("global_load_dwordx4 %0, %1, off" : "=&v"(dstv) : "v"(ptr))
#define VMWAIT(N)                                          \
  asm volatile("s_waitcnt vmcnt(" #N ")" ::: "memory");    \
  __builtin_amdgcn_sched_barrier(0)

// ---------------- Fused aggregate + GEMM ----------------
// Block = 4 independent waves, each owns 16 dst rows; wave = 4 groups of 16
// lanes; group g owns rows g*4..g*4+3, CONTIGUOUS in CSR -> one flat edge
// stream [b0, b0+P) walked in 2-edge pairs, double-buffered via inline-asm
// global_load_dwordx4 into named f32x4 regs (8 loads = 4KB/wave in flight,
// guaranteed: asm outputs can't be sunk) with counted vmcnt(4) waits.
// Row boundaries flush acc -> LDS tile. Phase B: 8x8 MFMA from own LDS tile
// x global b_tab. No barriers anywhere (waves never share LDS).
__global__ __launch_bounds__(256, 4) void fused_kernel(
    const float* __restrict__ x, const int* __restrict__ row_ptr,
    const int* __restrict__ sorted, const float* __restrict__ degree,
    const int* __restrict__ self_ids, const uint32_t* __restrict__ b_tab,
    float* __restrict__ out, int n_dst)
{
  __shared__ uint32_t As[4][16][132];   // per-wave tiles, stride 528B (2-way banks)
  const int tid = threadIdx.x;
  const int w = tid >> 6, lane = tid & 63;
  const int g = lane >> 4, li = lane & 15;
  const int g16 = g << 4, g4 = g << 2, li8 = li << 3;
  const int rbase = blockIdx.x * 64 + w * 16;

  // Wave-wide metadata prefetch.
  int rp = 0, sid_all = 0;
  float deg_all = 1.f;
  if (lane < 17) {
    const int idx = rbase + lane;
    rp = row_ptr[idx > n_dst ? n_dst : idx];
  }
  if (lane < 16) {
    const int r = rbase + lane;
    const int rc = (r < n_dst) ? r : 0;
    sid_all = self_ids[rc];
    deg_all = degree[rc];
  }

  const int b0 = __shfl(rp, g4 + 0);
  const int e1 = __shfl(rp, g4 + 1) - b0;   // row boundaries, relative
  const int e2 = __shfl(rp, g4 + 2) - b0;
  const int e3 = __shfl(rp, g4 + 3) - b0;
  const int P  = __shfl(rp, g4 + 4) - b0;
  const float inv0 = 1.0f / __shfl(deg_all, g4 + 0);
  const float inv1 = 1.0f / __shfl(deg_all, g4 + 1);
  const float inv2 = 1.0f / __shfl(deg_all, g4 + 2);
  const float inv3 = 1.0f / __shfl(deg_all, g4 + 3);

  float a0 = 0.f, a1 = 0.f, a2 = 0.f, a3 = 0.f;
  float a4 = 0.f, a5 = 0.f, a6 = 0.f, a7 = 0.f;
  int rcur = 0;

#define FLUSH1                                                              \
  {                                                                         \
    const float _iv = (rcur == 0) ? inv0 : (rcur == 1) ? inv1               \
                    : (rcur == 2) ? inv2 : inv3;                            \
    uint4 _pa;                                                              \
    _pa.x = pack2(a0 * _iv, a1 * _iv);                                      \
    _pa.y = pack2(a2 * _iv, a3 * _iv);                                      \
    _pa.z = pack2(a4 * _iv, a5 * _iv);                                      \
    _pa.w = pack2(a6 * _iv, a7 * _iv);                                      \
    *reinterpret_cast<uint4*>(&As[w][g4 + rcur][li * 4]) = _pa;             \
    a0 = a1 = a2 = a3 = a4 = a5 = a6 = a7 = 0.f;                            \
    ++rcur;                                                                 \
  }

#define ISSUE2(Va, Vb, Vc, Vd, E0)                                          \
  {                                                                         \
    const int _e0 = (E0);                                                   \
    if ((_e0 & 15) == 0) {                                                  \
      if (_e0 > 0) ids = idsN;                                              \
      const int _nb = _e0 + 16;                                             \
      idsN = (_nb < P && li < P - _nb) ? sorted[b0 + _nb + li] : 0;         \
    }                                                                       \
    int _s0 = __shfl(ids, g16 + (_e0 & 15));                                \
    int _s1 = __shfl(ids, g16 + ((_e0 + 1) & 15));                          \
    _s0 = (_e0 < P) ? _s0 : 0;                                              \
    _s1 = (_e0 + 1 < P) ? _s1 : 0;                                          \
    const float* _p0 = x + (size_t)_s0 * DIM + li8;                         \
    const float* _p1 = x + (size_t)_s1 * DIM + li8;                         \
    GLD(Va, _p0); GLD(Vb, _p0 + 4);                                         \
    GLD(Vc, _p1); GLD(Vd, _p1 + 4);                                         \
  }

#define CONSUME_E(Va, Vb, J)                                                \
  if ((J) < P) {                                                            \
    while (rcur < 3 &&                                                      \
           (J) >= ((rcur == 0) ? e1 : (rcur == 1) ? e2 : e3)) FLUSH1;       \
    a0 += Va[0]; a1 += Va[1]; a2 += Va[2]; a3 += Va[3];                     \
    a4 += Vb[0]; a5 += Vb[1]; a6 += Vb[2]; a7 += Vb[3];                     \
  }

  {
    int ids = (li < P) ? sorted[b0 + li] : 0;
    int idsN = 0;
    f32x4 A0, A1, A2, A3, B0, B1, B2, B3;
    if (P > 0) {
      ISSUE2(A0, A1, A2, A3, 0);
      int q = 0;
      for (;;) {
        if (q + 2 < P) {
          ISSUE2(B0, B1, B2, B3, q + 2);
          VMWAIT(4);
        } else {
          VMWAIT(0);
        }
        CONSUME_E(A0, A1, q);
        CONSUME_E(A2, A3, q + 1);
        q += 2;
        if (q >= P) break;
        if (q + 2 < P) {
          ISSUE2(A0, A1, A2, A3, q + 2);
          VMWAIT(4);
        } else {
          VMWAIT(0);
        }
        CONSUME_E(B0, B1, q);
        CONSUME_E(B2, B3, q + 1);
        q += 2;
        if (q >= P) break;
      }
    }
    while (rcur < 4) FLUSH1;
  }

  // Self rows (K=128..255): regular loads after the edge loop (one exposed
  // round-trip per wave; keeps loop-carried VGPR pressure low).
  {
    int sid[4];
#pragma unroll
    for (int r = 0; r < 4; ++r) sid[r] = __shfl(sid_all, g4 + r);
#pragma unroll
    for (int r = 0; r < 4; ++r) {
      const float4* xs = reinterpret_cast<const float4*>(x + (size_t)sid[r] * DIM + li8);
      const float4 t0 = xs[0], t1 = xs[1];
      uint4 ps;
      ps.x = pack2(t0.x, t0.y);
      ps.y = pack2(t0.z, t0.w);
      ps.z = pack2(t1.x, t1.y);
      ps.w = pack2(t1.z, t1.w);
      *reinterpret_cast<uint4*>(&As[w][g4 + r][64 + li * 4]) = ps;
    }
  }

  // Phase B: A-frag lane ln holds A[row=ln&15][k=kst*32+(ln>>4)*8+j], j=0..7.
  // Wave-synchronous (same wave wrote its whole tile): no barrier needed.
  const uint32_t* Arow = &As[w][lane & 15][(lane >> 4) << 2];
  const uint16_t* Bt = (const uint16_t*)b_tab;
  f32x4 acc[8] = {};
#pragma unroll
  for (int kst = 0; kst < 8; ++kst) {
    const short8 av = *reinterpret_cast<const short8*>(Arow + kst * 16);
#pragma unroll
    for (int ct = 0; ct < 8; ++ct) {
      const short8 bv = *reinterpret_cast<const short8*>(Bt + (kst * 8 + ct) * 512 + lane * 8);
      acc[ct] = __builtin_amdgcn_mfma_f32_16x16x32_bf16(av, bv, acc[ct], 0, 0, 0);
    }
  }

  // C/D (m89): col = lane&15, row = (lane>>4)*4 + reg.
  const int rout = rbase + ((lane >> 4) << 2);
  const int ccol = lane & 15;
#pragma unroll
  for (int ct = 0; ct < 8; ++ct) {
#pragma unroll
    for (int j = 0; j < 4; ++j) {
      const int row = rout + j;
      if (row < n_dst) out[(size_t)row * DIM + ct * 16 + ccol] = acc[ct][j];
    }
  }
#undef FLUSH1
#undef ISSUE2
#undef CONSUME_E
}

extern "C" void kernel_launch(void* const* d_in, const int* in_sizes, int n_in,
                              void* d_out, int out_size, void* d_ws, size_t ws_size,
                              hipStream_t stream) {
  const float* x        = (const float*)d_in[0];
  const float* W1       = (const float*)d_in[1];
  const float* W2       = (const float*)d_in[2];
  const float* degree   = (const float*)d_in[3];
  const int*   src_idx  = (const int*)d_in[4];
  const int*   dst_idx  = (const int*)d_in[5];
  const int*   self_ids = (const int*)d_in[6];
  float* out = (float*)d_out;
  const int n_dst  = in_sizes[3];
  const int n_edge = in_sizes[4];

  // ws: counts | row_ptr | cursor | bsum | sorted | b_tab  (~3.3 MB)
  auto align256 = [](size_t v) { return (v + 255) & ~(size_t)255; };
  char* ws = (char*)d_ws;
  size_t o_counts = 0;
  size_t o_rowptr = align256(o_counts + (size_t)n_dst * 4);
  size_t o_cursor = align256(o_rowptr + (size_t)(n_dst + 1) * 4);
  size_t o_bsum   = align256(o_cursor + (size_t)n_dst * 4);
  size_t o_sorted = align256(o_bsum + 1024 * 4);
  size_t o_btab   = align256(o_sorted + (size_t)n_edge * 4);
  int* counts  = (int*)(ws + o_counts);
  int* row_ptr = (int*)(ws + o_rowptr);
  int* cursor  = (int*)(ws + o_cursor);
  int* bsum    = (int*)(ws + o_bsum);
  int* sorted  = (int*)(ws + o_sorted);
  uint32_t* b_tab = (uint32_t*)(ws + o_btab);

  const int nb = (n_dst + 1023) >> 10;

  hipMemsetAsync(counts, 0, (size_t)n_dst * 4, stream);
  hist_kernel<<<(n_edge + 255) / 256, 256, 0, stream>>>(dst_idx, counts, n_edge,
                                                        W1, W2, b_tab);
  scan1_kernel<<<nb, 1024, 0, stream>>>(counts, row_ptr, bsum, n_dst);
  scan3_kernel<<<(n_dst + 255) / 256, 256, 0, stream>>>(row_ptr, cursor, bsum, n_dst);
  fill_kernel<<<(n_edge + 255) / 256, 256, 0, stream>>>(src_idx, dst_idx, cursor,
                                                        sorted, n_edge);
  fused_kernel<<<(n_dst + 63) / 64, 256, 0, stream>>>(x, row_ptr, sorted, degree,
                                                      self_ids, b_tab, out, n_dst);
}